// Round 3
// baseline (1962.437 us; speedup 1.0000x reference)
//
#include <hip/hip_runtime.h>

#define T_STEPS 1024
#define BATCH   64
#define NIN     32
#define NH      256
#define NOUT    16

typedef __attribute__((ext_vector_type(8))) _Float16 half8;
typedef __attribute__((ext_vector_type(4))) _Float16 half4;
typedef __attribute__((ext_vector_type(4))) float    f32x4;

__device__ __forceinline__ float fast_tanh(float x) {
  // tanh(x) = 1 - 2/(exp2(2*log2e*x)+1); exp2->inf/0 gives correct +-1 tails
  float e = __builtin_amdgcn_exp2f(x * 2.8853900817779268f);
  return 1.0f - 2.0f * __builtin_amdgcn_rcpf(e + 1.0f);
}

// LDS layout (unchanged from round 2, conflict-verified): rlds[buf][m][...]
// ushort, row stride 320 (40 blocks of 8); element n at blk=(n>>3)^(m&7),
// j=n&7; u (k=256..287) at blk=(32+q)^(m&7).
#define ROW 320
#define BUFSZ (16 * ROW)

// NO s_barrier in the time loop. Sync is per-chunk producer flags:
//   prod[w] = t+1  <=>  wave w has written its r_t chunk (k in [32w,32w+32))
//                       (+ u_{t+1} for w==1) into buf[1-(t&1)].
// Consumer at step t reads chunk c after prod[c] >= t. Passing all 9 polls
// also proves every wave finished step t-1's READS, so overwriting the
// other buffer (which holds r_{t-2}) is safe -- 2 buffers suffice.
#define STEP_BODY(TCUR, RB, WB, QREG)                                        \
  {                                                                          \
    const int t = (TCUR);                                                    \
    /* wave 1: u_{t+1} load issued early (staged to LDS at end of step) */   \
    f32x4 ua, ub;                                                            \
    if (w == 1) {                                                            \
      const int tu = (t + 1 < T_STEPS) ? t + 1 : T_STEPS - 1;                \
      const float* up = inputs + ((size_t)tu * BATCH + b) * NIN + 8 * q;     \
      ua = *(const f32x4*)up;                                                \
      ub = *(const f32x4*)(up + 4);                                          \
    }                                                                        \
    /* acc = q_t + 0.1*brec + ... ; q_t was loaded 2 steps ago (deep pf) */  \
    f32x4 acc[2];                                                            \
    acc[0] = brecs[0] + QREG[0];                                             \
    acc[1] = brecs[1] + QREG[1];                                             \
    {  /* reload QREG with q_{t+2}: 2 full steps of latency slack */         \
      const int tq = (t + 2 < T_STEPS) ? t + 2 : T_STEPS - 1;                \
      const float* qp = noise + ((size_t)tq * BATCH + b) * NH + 32 * w + 4 * q; \
      QREG[0] = *(const f32x4*)qp;                                           \
      QREG[1] = *(const f32x4*)(qp + 16);                                    \
    }                                                                        \
    f32x4 zac = bout4;                                                       \
    int fl = vflags[0];                                                      \
    _Pragma("unroll")                                                        \
    for (int kt = 0; kt < 9; ++kt) {                                         \
      const int own = (kt < 8) ? kt : 1;                                     \
      while (fl < t) fl = vflags[own];         /* spin (rare) */             \
      if (kt < 8) fl = vflags[(kt + 1 < 8) ? kt + 1 : 1]; /* pre-issue */    \
      asm volatile("" ::: "memory");  /* no hoisting reads above the poll */ \
      const int blk = (4 * kt + q) ^ mx;                                     \
      const half8 bf = *(const half8*)&rlds[(RB) + m * ROW + blk * 8];       \
      acc[0] = __builtin_amdgcn_mfma_f32_16x16x32_f16(wr[0][kt], bf, acc[0], 0, 0, 0); \
      acc[1] = __builtin_amdgcn_mfma_f32_16x16x32_f16(wr[1][kt], bf, acc[1], 0, 0, 0); \
      if (w == 0 && kt < 8)                                                  \
        zac = __builtin_amdgcn_mfma_f32_16x16x32_f16(wo[kt], bf, zac, 0, 0, 0); \
    }                                                                        \
    _Pragma("unroll")                                                        \
    for (int nt = 0; nt < 2; ++nt) {                                         \
      x[nt] = 0.9f * x[nt] + acc[nt];                                        \
      const int n0 = 32 * w + 16 * nt + 4 * q;                               \
      *(f32x4*)(outx + ((size_t)t * BATCH + b) * NH + n0) = x[nt];           \
    }                                                                        \
    if (w == 0 && t > 0)                                                     \
      *(f32x4*)(outz + ((size_t)(t - 1) * BATCH + b) * NOUT + 4 * q) = zac;  \
    _Pragma("unroll")                                                        \
    for (int nt = 0; nt < 2; ++nt) {                                         \
      const int n0 = 32 * w + 16 * nt + 4 * q;                               \
      half4 r;                                                               \
      r.x = (_Float16)fast_tanh(x[nt].x);                                    \
      r.y = (_Float16)fast_tanh(x[nt].y);                                    \
      r.z = (_Float16)fast_tanh(x[nt].z);                                    \
      r.w = (_Float16)fast_tanh(x[nt].w);                                    \
      const int blk = (n0 >> 3) ^ mx;                                        \
      *(half4*)&rlds[(WB) + m * ROW + blk * 8 + (n0 & 7)] = r;               \
    }                                                                        \
    if (w == 1) {                                                            \
      half8 uu;                                                              \
      uu[0]=(_Float16)ua.x; uu[1]=(_Float16)ua.y; uu[2]=(_Float16)ua.z; uu[3]=(_Float16)ua.w; \
      uu[4]=(_Float16)ub.x; uu[5]=(_Float16)ub.y; uu[6]=(_Float16)ub.z; uu[7]=(_Float16)ub.w; \
      const int blk = (32 + q) ^ mx;                                         \
      *(half8*)&rlds[(WB) + m * ROW + blk * 8] = uu;                         \
    }                                                                        \
    asm volatile("s_waitcnt lgkmcnt(0)" ::: "memory"); /* data before flag */\
    if (l == 0) ((volatile int*)prodf)[w] = t + 1;                           \
  }

__global__ __launch_bounds__(512, 2)
void RecurrentNetwork_19628000543215_kernel(
    const float* __restrict__ inputs,  // [T][B][NIN]
    const float* __restrict__ noise,   // [T][B][NH]
    const float* __restrict__ x0,      // [B][NH]
    const float* __restrict__ Win,     // [NIN][NH]
    const float* __restrict__ Wrec,    // [NH][NH]
    const float* __restrict__ brec,    // [NH]
    const float* __restrict__ Wout,    // [NH][NOUT]
    const float* __restrict__ bout,    // [NOUT]
    float* __restrict__ out)           // outputs [T][B][NOUT] ++ states [T][B][NH]
{
  __shared__ alignas(16) unsigned short rlds[2 * BUFSZ];
  __shared__ int prodf[8];
  const volatile int* vflags = (const volatile int*)prodf;

  const int g   = blockIdx.x;       // batch group: batches [16g, 16g+16)
  const int tid = threadIdx.x;
  const int w   = tid >> 6;         // wave 0..7: owns n-columns [32w, 32w+32)
  const int l   = tid & 63;
  const int m   = l & 15;           // batch-in-group (B col / C col)
  const int q   = l >> 4;           // quad
  const int b   = 16 * g + m;      // global batch
  const int mx  = m & 7;            // LDS swizzle key

  float* outz = out;
  float* outx = out + (size_t)T_STEPS * BATCH * NOUT;

  if (tid < 8) prodf[tid] = 0;

  // ---- weights -> persistent register A-frags, ALPHA pre-folded ----
  half8 wr[2][9];                   // kt 0..7 = 0.1*Wrec^T, kt 8 = 0.1*Win^T
  #pragma unroll
  for (int nt = 0; nt < 2; ++nt) {
    const int n = 32 * w + 16 * nt + m;
    #pragma unroll
    for (int kt = 0; kt < 9; ++kt) {
      #pragma unroll
      for (int j = 0; j < 8; ++j) {
        const int k = 32 * kt + 8 * q + j;
        const float v = (kt < 8) ? Wrec[(size_t)k * NH + n]
                                 : Win[(size_t)(k - 256) * NH + n];
        wr[nt][kt][j] = (_Float16)(0.1f * v);
      }
    }
  }
  half8 wo[8];                      // Wout^T A-frags (z-tile), UNSCALED
  if (w == 0) {
    #pragma unroll
    for (int kt = 0; kt < 8; ++kt)
      #pragma unroll
      for (int j = 0; j < 8; ++j)
        wo[kt][j] = (_Float16)Wout[(size_t)(32 * kt + 8 * q + j) * NOUT + m];
  }

  f32x4 brecs[2], x[2];
  #pragma unroll
  for (int nt = 0; nt < 2; ++nt) {
    const int n0 = 32 * w + 16 * nt + 4 * q;
    brecs[nt] = 0.1f * (*(const f32x4*)(brec + n0));
    x[nt]     = *(const f32x4*)(x0 + (size_t)b * NH + n0);
  }
  const f32x4 bout4 = *(const f32x4*)(bout + 4 * q);

  // ---- preloop: r_{-1}=tanh(x0), u_0 -> buf0; q_0,q_1 -> regs ----
  #pragma unroll
  for (int nt = 0; nt < 2; ++nt) {
    const int n0 = 32 * w + 16 * nt + 4 * q;
    half4 r;
    r.x = (_Float16)fast_tanh(x[nt].x);
    r.y = (_Float16)fast_tanh(x[nt].y);
    r.z = (_Float16)fast_tanh(x[nt].z);
    r.w = (_Float16)fast_tanh(x[nt].w);
    const int blk = (n0 >> 3) ^ mx;
    *(half4*)&rlds[m * ROW + blk * 8 + (n0 & 7)] = r;
  }
  if (w == 1) {
    const float* up = inputs + (size_t)b * NIN + 8 * q;   // t = 0
    const f32x4 ua = *(const f32x4*)up;
    const f32x4 ub = *(const f32x4*)(up + 4);
    half8 uu;
    uu[0]=(_Float16)ua.x; uu[1]=(_Float16)ua.y; uu[2]=(_Float16)ua.z; uu[3]=(_Float16)ua.w;
    uu[4]=(_Float16)ub.x; uu[5]=(_Float16)ub.y; uu[6]=(_Float16)ub.z; uu[7]=(_Float16)ub.w;
    const int blk = (32 + q) ^ mx;
    *(half8*)&rlds[m * ROW + blk * 8] = uu;
  }
  f32x4 qA[2], qB[2];
  qA[0] = *(const f32x4*)(noise + (size_t)b * NH + 32 * w + 4 * q);          // q_0
  qA[1] = *(const f32x4*)(noise + (size_t)b * NH + 32 * w + 16 + 4 * q);
  qB[0] = *(const f32x4*)(noise + ((size_t)BATCH + b) * NH + 32 * w + 4 * q);       // q_1
  qB[1] = *(const f32x4*)(noise + ((size_t)BATCH + b) * NH + 32 * w + 16 + 4 * q);
  __syncthreads();

  // ---- time loop, unrolled by 2 (static buffer offsets, qA/qB rotation) ----
  #pragma unroll 1
  for (int t2 = 0; t2 < T_STEPS; t2 += 2) {
    STEP_BODY(t2,     0,     BUFSZ, qA)
    STEP_BODY(t2 + 1, BUFSZ, 0,     qB)
  }

  // ---- epilogue: z_{T-1} from r_{T-1} (in buf0 after t=1023) ----
  if (w == 0) {
    f32x4 zac = bout4;
    int fl = vflags[0];
    #pragma unroll
    for (int kt = 0; kt < 8; ++kt) {
      while (fl < T_STEPS) fl = vflags[kt];
      if (kt < 7) fl = vflags[kt + 1];
      asm volatile("" ::: "memory");
      const int blk = (4 * kt + q) ^ mx;
      const half8 bf = *(const half8*)&rlds[m * ROW + blk * 8];
      zac = __builtin_amdgcn_mfma_f32_16x16x32_f16(wo[kt], bf, zac, 0, 0, 0);
    }
    *(f32x4*)(outz + ((size_t)(T_STEPS - 1) * BATCH + b) * NOUT + 4 * q) = zac;
  }
}

extern "C" void kernel_launch(void* const* d_in, const int* in_sizes, int n_in,
                              void* d_out, int out_size, void* d_ws, size_t ws_size,
                              hipStream_t stream) {
  (void)in_sizes; (void)n_in; (void)out_size; (void)d_ws; (void)ws_size;
  RecurrentNetwork_19628000543215_kernel<<<dim3(4), dim3(512), 0, stream>>>(
      (const float*)d_in[0],   // inputs
      (const float*)d_in[1],   // noise
      (const float*)d_in[2],   // x0
      (const float*)d_in[3],   // Win
      (const float*)d_in[4],   // Wrec
      (const float*)d_in[5],   // brec
      (const float*)d_in[6],   // Wout
      (const float*)d_in[7],   // bout
      (float*)d_out);
}

// Round 4
// 1359.418 us; speedup vs baseline: 1.4436x; 1.4436x over previous
//
#include <hip/hip_runtime.h>

#define T_STEPS 1024
#define BATCH   64
#define NIN     32
#define NH      256
#define NOUT    16

typedef __attribute__((ext_vector_type(8))) _Float16 half8;
typedef __attribute__((ext_vector_type(4))) _Float16 half4;
typedef __attribute__((ext_vector_type(4))) float    f32x4;

__device__ __forceinline__ float fast_tanh(float x) {
  // tanh(x) = 1 - 2/(exp2(2*log2e*x)+1); exp2->inf/0 gives correct +-1 tails
  float e = __builtin_amdgcn_exp2f(x * 2.8853900817779268f);
  return 1.0f - 2.0f * __builtin_amdgcn_rcpf(e + 1.0f);
}

// LDS layout (round-2, conflict-verified): rlds[buf][m][...] ushort, row
// stride 320 (40 blocks of 8); element n at blk=(n>>3)^(m&7), j=n&7;
// u (k=256..287) at blk=(32+q)^(m&7).
#define ROW 320
#define BUFSZ (16 * 320)

// Sync: NO s_barrier in the time loop. prod[w]=t+1 <=> wave w wrote its r_t
// chunk (k in [32w,32w+32), + u_{t+1} for w==1) into buf[(t+1)&1].
// Poll is ONE ballot at step top (lane l watches prodf[l&7]) so the K-loop
// has no interleaved volatile reads (round-3 lesson: in-order lgkmcnt turns
// per-chunk polls into per-b128 serialization).
// Buffer safety: prod[w]>=t  =>  w finished step t-1 READS (writes come
// after reads), so overwriting the buffer read at t-1 is safe.

__global__ __launch_bounds__(512, 2)
void RecurrentNetwork_19628000543215_kernel(
    const float* __restrict__ inputs,  // [T][B][NIN]
    const float* __restrict__ noise,   // [T][B][NH]
    const float* __restrict__ x0,      // [B][NH]
    const float* __restrict__ Win,     // [NIN][NH]
    const float* __restrict__ Wrec,    // [NH][NH]
    const float* __restrict__ brec,    // [NH]
    const float* __restrict__ Wout,    // [NH][NOUT]
    const float* __restrict__ bout,    // [NOUT]
    float* __restrict__ out)           // outputs [T][B][NOUT] ++ states [T][B][NH]
{
  __shared__ alignas(16) unsigned short rlds[2 * BUFSZ];
  __shared__ int prodf[8];
  volatile int* vflags = (volatile int*)prodf;

  const int g   = blockIdx.x;       // batch group: batches [16g, 16g+16)
  const int tid = threadIdx.x;
  const int w   = tid >> 6;         // wave 0..7: owns n-columns [32w, 32w+32)
  const int l   = tid & 63;
  const int m   = l & 15;           // batch-in-group (B col / C col)
  const int q   = l >> 4;           // quad
  const int b   = 16 * g + m;       // global batch
  const int mx  = m & 7;            // LDS swizzle key

  float* outz = out;
  float* outx = out + (size_t)T_STEPS * BATCH * NOUT;

  if (tid < 8) prodf[tid] = 0;

  // ---- weights -> persistent register A-frags, ALPHA pre-folded ----
  // A-frag (16x16x32): row = lane&15, k = (lane>>4)*8 + j; lane->k map only
  // has to MATCH the r/u LDS layout (contraction is permutation-invariant).
  half8 wr[2][9];                   // kt 0..7 = 0.1*Wrec^T, kt 8 = 0.1*Win^T
  #pragma unroll
  for (int nt = 0; nt < 2; ++nt) {
    const int n = 32 * w + 16 * nt + m;
    #pragma unroll
    for (int kt = 0; kt < 9; ++kt) {
      #pragma unroll
      for (int j = 0; j < 8; ++j) {
        const int k = 32 * kt + 8 * q + j;
        const float v = (kt < 8) ? Wrec[(size_t)k * NH + n]
                                 : Win[(size_t)(k - 256) * NH + n];
        wr[nt][kt][j] = (_Float16)(0.1f * v);
      }
    }
  }
  half8 wo[8];                      // Wout^T A-frags (z-tile), UNSCALED
  if (w == 0) {
    #pragma unroll
    for (int kt = 0; kt < 8; ++kt)
      #pragma unroll
      for (int j = 0; j < 8; ++j)
        wo[kt][j] = (_Float16)Wout[(size_t)(32 * kt + 8 * q + j) * NOUT + m];
  }

  f32x4 brecs[2], x[2];
  #pragma unroll
  for (int nt = 0; nt < 2; ++nt) {
    const int n0 = 32 * w + 16 * nt + 4 * q;
    brecs[nt] = 0.1f * (*(const f32x4*)(brec + n0));
    x[nt]     = *(const f32x4*)(x0 + (size_t)b * NH + n0);
  }
  const f32x4 bout4 = *(const f32x4*)(bout + 4 * q);

  // ---- preloop: r_{-1}=tanh(x0), u_0 -> buf0; q_0 -> regs ----
  #pragma unroll
  for (int nt = 0; nt < 2; ++nt) {
    const int n0 = 32 * w + 16 * nt + 4 * q;
    half4 r;
    r.x = (_Float16)fast_tanh(x[nt].x);
    r.y = (_Float16)fast_tanh(x[nt].y);
    r.z = (_Float16)fast_tanh(x[nt].z);
    r.w = (_Float16)fast_tanh(x[nt].w);
    const int blk = (n0 >> 3) ^ mx;
    *(half4*)&rlds[m * ROW + blk * 8 + (n0 & 7)] = r;
  }
  if (w == 1) {
    const float* up = inputs + (size_t)b * NIN + 8 * q;   // t = 0
    const f32x4 ua = *(const f32x4*)up;
    const f32x4 ub = *(const f32x4*)(up + 4);
    half8 uu;
    uu[0]=(_Float16)ua.x; uu[1]=(_Float16)ua.y; uu[2]=(_Float16)ua.z; uu[3]=(_Float16)ua.w;
    uu[4]=(_Float16)ub.x; uu[5]=(_Float16)ub.y; uu[6]=(_Float16)ub.z; uu[7]=(_Float16)ub.w;
    const int blk = (32 + q) ^ mx;
    *(half8*)&rlds[m * ROW + blk * 8] = uu;
  }
  f32x4 qv[2];
  qv[0] = *(const f32x4*)(noise + (size_t)b * NH + 32 * w + 4 * q);   // q_0
  qv[1] = *(const f32x4*)(noise + (size_t)b * NH + 32 * w + 16 + 4 * q);
  __syncthreads();

  int myfl = 0;                     // last-seen prodf[l&7]

  // ---- time loop ----
  #pragma unroll 1
  for (int t = 0; t < T_STEPS; ++t) {
    const int rb = (t & 1) * BUFSZ;
    const int wb = BUFSZ - rb;
    const int tn = (t + 1 < T_STEPS) ? t + 1 : T_STEPS - 1;

    // single poll point: all producers must have written step t-1
    while (__ballot(myfl >= t) != ~0ull) myfl = vflags[l & 7];
    asm volatile("" ::: "memory");  // no LDS reads hoisted above the poll

    f32x4 ua, ub;                   // wave 1: u_{t+1} load issued early
    if (w == 1) {
      const float* up = inputs + ((size_t)tn * BATCH + b) * NIN + 8 * q;
      ua = *(const f32x4*)up;
      ub = *(const f32x4*)(up + 4);
    }
    // q_{t+1} prefetch (consumed AFTER next step's K-loop => ~1.5 steps slack)
    f32x4 qn0 = *(const f32x4*)(noise + ((size_t)tn * BATCH + b) * NH + 32 * w + 4 * q);
    f32x4 qn1 = *(const f32x4*)(noise + ((size_t)tn * BATCH + b) * NH + 32 * w + 16 + 4 * q);

    // acc = 0.1*brec + r_{t-1}@(0.1*Wrec) + u_t@(0.1*Win)   [q_t added later]
    f32x4 acc[2];
    acc[0] = brecs[0];
    acc[1] = brecs[1];
    f32x4 zac = bout4;              // z_{t-1} = bout + r_{t-1}@Wout (wave 0)

    #pragma unroll
    for (int kt = 0; kt < 9; ++kt) {
      const int blk = (4 * kt + q) ^ mx;
      const half8 bf = *(const half8*)&rlds[rb + m * ROW + blk * 8];
      acc[0] = __builtin_amdgcn_mfma_f32_16x16x32_f16(wr[0][kt], bf, acc[0], 0, 0, 0);
      acc[1] = __builtin_amdgcn_mfma_f32_16x16x32_f16(wr[1][kt], bf, acc[1], 0, 0, 0);
      if (w == 0 && kt < 8)
        zac = __builtin_amdgcn_mfma_f32_16x16x32_f16(wo[kt], bf, zac, 0, 0, 0);
    }

    // x_t = 0.9*x_{t-1} + acc + q_t ; store states[t]
    #pragma unroll
    for (int nt = 0; nt < 2; ++nt) {
      x[nt] = 0.9f * x[nt] + acc[nt] + qv[nt];
      const int n0 = 32 * w + 16 * nt + 4 * q;
      *(f32x4*)(outx + ((size_t)t * BATCH + b) * NH + n0) = x[nt];
    }

    if (w == 0 && t > 0)            // store z_{t-1} (fire-and-forget)
      *(f32x4*)(outz + ((size_t)(t - 1) * BATCH + b) * NOUT + 4 * q) = zac;

    // r_t = tanh(x_t) -> fp16 -> buf[(t+1)&1]
    #pragma unroll
    for (int nt = 0; nt < 2; ++nt) {
      const int n0 = 32 * w + 16 * nt + 4 * q;
      half4 r;
      r.x = (_Float16)fast_tanh(x[nt].x);
      r.y = (_Float16)fast_tanh(x[nt].y);
      r.z = (_Float16)fast_tanh(x[nt].z);
      r.w = (_Float16)fast_tanh(x[nt].w);
      const int blk = (n0 >> 3) ^ mx;
      *(half4*)&rlds[wb + m * ROW + blk * 8 + (n0 & 7)] = r;
    }

    if (w == 1) {                   // stage u_{t+1}
      half8 uu;
      uu[0]=(_Float16)ua.x; uu[1]=(_Float16)ua.y; uu[2]=(_Float16)ua.z; uu[3]=(_Float16)ua.w;
      uu[4]=(_Float16)ub.x; uu[5]=(_Float16)ub.y; uu[6]=(_Float16)ub.z; uu[7]=(_Float16)ub.w;
      const int blk = (32 + q) ^ mx;
      *(half8*)&rlds[wb + m * ROW + blk * 8] = uu;
    }

    qv[0] = qn0;                    // q_{t+1} now owned
    qv[1] = qn1;

    // publish: data drained (lgkm in-order) THEN flag
    asm volatile("s_waitcnt lgkmcnt(0)" ::: "memory");
    if (l == 0) vflags[w] = t + 1;
    myfl = vflags[l & 7];           // early re-read for next step's poll
  }

  // ---- epilogue: z_{T-1} from r_{T-1} (in buf0 after t=1023) ----
  if (w == 0) {
    while (__ballot(myfl >= T_STEPS) != ~0ull) myfl = vflags[l & 7];
    asm volatile("" ::: "memory");
    f32x4 zac = bout4;
    #pragma unroll
    for (int kt = 0; kt < 8; ++kt) {
      const int blk = (4 * kt + q) ^ mx;
      const half8 bf = *(const half8*)&rlds[m * ROW + blk * 8];
      zac = __builtin_amdgcn_mfma_f32_16x16x32_f16(wo[kt], bf, zac, 0, 0, 0);
    }
    *(f32x4*)(outz + ((size_t)(T_STEPS - 1) * BATCH + b) * NOUT + 4 * q) = zac;
  }
}

extern "C" void kernel_launch(void* const* d_in, const int* in_sizes, int n_in,
                              void* d_out, int out_size, void* d_ws, size_t ws_size,
                              hipStream_t stream) {
  (void)in_sizes; (void)n_in; (void)out_size; (void)d_ws; (void)ws_size;
  RecurrentNetwork_19628000543215_kernel<<<dim3(4), dim3(512), 0, stream>>>(
      (const float*)d_in[0],   // inputs
      (const float*)d_in[1],   // noise
      (const float*)d_in[2],   // x0
      (const float*)d_in[3],   // Win
      (const float*)d_in[4],   // Wrec
      (const float*)d_in[5],   // brec
      (const float*)d_in[6],   // Wout
      (const float*)d_in[7],   // bout
      (float*)d_out);
}